// Round 8
// baseline (448.778 us; speedup 1.0000x reference)
//
#include <hip/hip_runtime.h>
#include <hip/hip_bf16.h>

typedef __bf16 bf16x8 __attribute__((ext_vector_type(8)));
typedef __bf16 bf16x4 __attribute__((ext_vector_type(4)));
typedef float f32x4 __attribute__((ext_vector_type(4)));

#define S_LEN 2048
#define HID 2560
#define NH 32
#define NKV 8
#define HD 128
#define QSZ 4096      // NH*HD
#define KVSZ 1024     // NKV*HD
#define QKV_N 6144    // QSZ + 2*KVSZ
#define SCALE_Q 0.08838834764831845f  // 128^-0.5
#define LOG2_THETA 13.287712379549449f // log2(10000)

#define ASM_VMCNT(n) asm volatile("s_waitcnt vmcnt(" #n ")" ::: "memory")
#define ASM_BAR()    asm volatile("s_barrier" ::: "memory")

// ---------------- f32 -> bf16 cast ----------------
__global__ void castk(const float* __restrict__ in, __bf16* __restrict__ out, int n4) {
  int i = blockIdx.x * blockDim.x + threadIdx.x;
  int stride = gridDim.x * blockDim.x;
  for (; i < n4; i += stride) {
    float4 v = ((const float4*)in)[i];
    bf16x4 o;
    o[0] = (__bf16)v.x; o[1] = (__bf16)v.y; o[2] = (__bf16)v.z; o[3] = (__bf16)v.w;
    ((bf16x4*)out)[i] = o;
  }
}

// ---------------- async global->LDS helper ----------------
__device__ __forceinline__ void gload16(const void* g, void* l) {
  __builtin_amdgcn_global_load_lds((const __attribute__((address_space(1))) void*)g,
                                   (__attribute__((address_space(3))) void*)l, 16, 0, 0);
}

// ---------------- 8-phase 256x256 bf16 GEMM: C = A[M][K] * B[N][K]^T ----------------
// 512 threads = 8 waves (2M x 4N), BK=64, 128KiB dynamic LDS = 2 dbuf x 4 half-slots
// (A-ks0, B-ks0, A-ks1, B-ks1; each 256rows x 32k x bf16 = 16KB).
// Half n = kt*4+h staged at phase n-6 (prefetch 6); counted vmcnt(8) at odd phases
// (K-split halves die progressively -> overwrite-safe, proven by phase algebra).
// LDS swizzle: 16B-chunk' = chunk ^ (row&3), applied on global source AND ds_read.
__global__ __launch_bounds__(512, 2) void gemm256(
    const __bf16* __restrict__ A, const __bf16* __restrict__ B, float* __restrict__ C,
    int M, int N, int K) {
  extern __shared__ __bf16 lds[];   // 65536 elems = 128 KiB
  const int t = threadIdx.x, w = t >> 6, l = t & 63;
  const int wr = w >> 2, wc = w & 3;
  const int lg = l >> 4, li = l & 15;
  const int bn = blockIdx.x, bm = blockIdx.y;
  const int NKT = K >> 6;

  f32x4 acc[8][4];
#pragma unroll
  for (int i = 0; i < 8; ++i)
#pragma unroll
    for (int j = 0; j < 4; ++j) acc[i][j] = (f32x4){0.f, 0.f, 0.f, 0.f};

  // stage half-tile n: slot (n&7), 1024 x 16B, 2 gloads/thread
  auto STG = [&](int n) {
    const int kt = n >> 2, h = n & 3;
    const int kcol = kt * 64 + (h >> 1) * 32;
    __bf16* dst = &lds[(size_t)(((kt & 1) << 2) + h) << 13];
    const __bf16* srcb = (h & 1) ? (B + (size_t)(bn * 256) * K)
                                 : (A + (size_t)(bm * 256) * K);
#pragma unroll
    for (int j = 0; j < 2; ++j) {
      const int idx = j * 512 + t;                    // 0..1023
      const int row = idx >> 2;                       // 0..255
      const int col = (((idx & 3) ^ (row & 3)) << 3); // swizzled 16B chunk
      gload16(srcb + (size_t)row * K + kcol + col,
              dst + j * 4096 + w * 512);              // wave-uniform LDS base
    }
  };
  // fragment read from half (buf, h): row lrow, k-chunk lg, swizzled
  auto RD = [&](int buf, int h, int lrow) -> bf16x8 {
    const int off = (lrow << 5) + ((lg ^ (lrow & 3)) << 3);
    return *(const bf16x8*)&lds[((size_t)(((buf << 2) + h)) << 13) + off];
  };

  for (int n = 0; n < 6; ++n) STG(n);
  ASM_VMCNT(8);              // halves 0,1 landed (12 issued - 8)
  ASM_BAR();

  for (int kt = 0; kt < NKT; ++kt) {
    const int buf = kt & 1;
#pragma unroll
    for (int q = 0; q < 4; ++q) {
      const int ks = q >> 1, mh = q & 1;
      bf16x8 a[4], b[4];
#pragma unroll
      for (int i = 0; i < 4; ++i)
        a[i] = RD(buf, ks * 2,     wr * 128 + mh * 64 + i * 16 + li);
#pragma unroll
      for (int j = 0; j < 4; ++j)
        b[j] = RD(buf, ks * 2 + 1, wc * 64 + j * 16 + li);
      const int s = kt * 4 + q;
      if (s + 6 < NKT * 4) STG(s + 6);
      ASM_BAR();
      __builtin_amdgcn_s_setprio(1);
#pragma unroll
      for (int i = 0; i < 4; ++i)
#pragma unroll
        for (int j = 0; j < 4; ++j)
          acc[mh * 4 + i][j] = __builtin_amdgcn_mfma_f32_16x16x32_bf16(
              a[i], b[j], acc[mh * 4 + i][j], 0, 0, 0);
      __builtin_amdgcn_s_setprio(0);
      if (q & 1) {           // K-half boundary: counted wait, drain 8->4->0
        if (s < 4 * NKT - 5)       ASM_VMCNT(8);
        else if (s == 4 * NKT - 5) ASM_VMCNT(4);
        else if (s == 4 * NKT - 3) ASM_VMCNT(0);
      }
      ASM_BAR();
    }
  }

  float* cp = C + (size_t)(bm * 256 + wr * 128 + lg * 4) * N + bn * 256 + wc * 64 + li;
#pragma unroll
  for (int fm = 0; fm < 8; ++fm)
#pragma unroll
    for (int fn = 0; fn < 4; ++fn)
#pragma unroll
      for (int r = 0; r < 4; ++r)
        cp[(size_t)(fm * 16 + r) * N + fn * 16] = acc[fm][fn][r];
}

// ---------------- bf16 GEMM (m97 128^2): C[M][N] = A[M][K] * B[N][K]^T ----------------
__global__ __launch_bounds__(256, 2) void gemm_bt(
    const __bf16* __restrict__ A, const __bf16* __restrict__ B, float* __restrict__ C,
    int M, int N, int K) {
  __shared__ __attribute__((aligned(16))) __bf16 lta[128 * 32];
  __shared__ __attribute__((aligned(16))) __bf16 ltb[128 * 32];
  const int t = threadIdx.x, w = t >> 6, l = t & 63;
  const int bn = blockIdx.x, bm = blockIdx.y;
  const int wr = w >> 1, wc = w & 1;
  const int lg = l >> 4, li = l & 15;

  f32x4 acc[4][4];
#pragma unroll
  for (int i = 0; i < 4; ++i)
#pragma unroll
    for (int j = 0; j < 4; ++j) acc[i][j] = (f32x4){0.f, 0.f, 0.f, 0.f};

  const int nkt = K >> 5;
  const int c0 = w * 2, c1 = w * 2 + 1;
  const int row0 = c0 * 16 + (l >> 2), row1 = c1 * 16 + (l >> 2);
  const int cole = (l & 3) * 8;
  const __bf16* ga = A + (size_t)(bm * 128) * K + cole;
  const __bf16* gb = B + (size_t)(bn * 128) * K + cole;

  for (int kt = 0; kt < nkt; ++kt) {
    const size_t ko = (size_t)kt * 32;
    gload16(ga + (size_t)row0 * K + ko, &lta[c0 * 512]);
    gload16(gb + (size_t)row0 * K + ko, &ltb[c0 * 512]);
    gload16(ga + (size_t)row1 * K + ko, &lta[c1 * 512]);
    gload16(gb + (size_t)row1 * K + ko, &ltb[c1 * 512]);
    __syncthreads();
    bf16x8 af[4], bfr[4];
#pragma unroll
    for (int f = 0; f < 4; ++f) {
      af[f]  = *(const bf16x8*)&lta[(wr * 64 + f * 16 + li) * 32 + lg * 8];
      bfr[f] = *(const bf16x8*)&ltb[(wc * 64 + f * 16 + li) * 32 + lg * 8];
    }
#pragma unroll
    for (int fm = 0; fm < 4; ++fm)
#pragma unroll
      for (int fn = 0; fn < 4; ++fn)
        acc[fm][fn] = __builtin_amdgcn_mfma_f32_16x16x32_bf16(af[fm], bfr[fn], acc[fm][fn], 0, 0, 0);
    __syncthreads();
  }

  float* cp = C + (size_t)(bm * 128 + wr * 64 + lg * 4) * N + bn * 128 + wc * 64 + li;
#pragma unroll
  for (int fm = 0; fm < 4; ++fm)
#pragma unroll
    for (int fn = 0; fn < 4; ++fn)
#pragma unroll
      for (int r = 0; r < 4; ++r)
        cp[(size_t)(fm * 16 + r) * N + fn * 16] = acc[fm][fn][r];
}

// ---------------- fused RMSNorm + RoPE, write bf16 q/k ----------------
__global__ __launch_bounds__(64) void norm_rope(
    const float* __restrict__ qkv, const int* __restrict__ positions,
    const float* __restrict__ qw, const float* __restrict__ kw,
    __bf16* __restrict__ q_bf, __bf16* __restrict__ k_bf) {
  const int s = blockIdx.x, hh = blockIdx.y, l = threadIdx.x;
  const float* row;
  const float* wgt;
  __bf16* outp;
  float scale;
  if (hh < NH) {
    row = qkv + (size_t)s * QKV_N + hh * HD;
    wgt = qw;
    outp = q_bf + ((size_t)s * NH + hh) * HD;
    scale = SCALE_Q;
  } else {
    row = qkv + (size_t)s * QKV_N + QSZ + (hh - NH) * HD;
    wgt = kw;
    outp = k_bf + ((size_t)s * NKV + (hh - NH)) * HD;
    scale = 1.0f;
  }
  float x1 = row[l], x2 = row[l + 64];
  float ss = x1 * x1 + x2 * x2;
#pragma unroll
  for (int off = 32; off; off >>= 1) ss += __shfl_xor(ss, off, 64);
  float rs = rsqrtf(ss * (1.0f / 128.0f) + 1e-6f);
  float n1 = x1 * rs * wgt[l], n2 = x2 * rs * wgt[l + 64];
  float ang = (float)positions[s] * exp2f((float)l * (-LOG2_THETA / 64.0f));
  float sn, cs;
  sincosf(ang, &sn, &cs);
  outp[l]      = (__bf16)((n1 * cs - n2 * sn) * scale);
  outp[l + 64] = (__bf16)((n2 * cs + n1 * sn) * scale);
}

// ---------------- V transpose: qkv f32 -> vt_bf[hk][d][s] ----------------
__global__ __launch_bounds__(256) void v_prep(const float* __restrict__ qkv, __bf16* __restrict__ vt) {
  const int s0 = blockIdx.x * 32, hk = blockIdx.y;
  __shared__ float lv[32][129];
  const int t = threadIdx.x;
  {
    const int s = t >> 3, dseg = (t & 7) * 16;
    const float* src = qkv + (size_t)(s0 + s) * QKV_N + (QSZ + KVSZ) + hk * HD + dseg;
#pragma unroll
    for (int j = 0; j < 4; ++j) {
      float4 v = *(const float4*)(src + j * 4);
      lv[s][dseg + j * 4 + 0] = v.x;
      lv[s][dseg + j * 4 + 1] = v.y;
      lv[s][dseg + j * 4 + 2] = v.z;
      lv[s][dseg + j * 4 + 3] = v.w;
    }
  }
  __syncthreads();
  {
    const int d = t >> 1, sh = (t & 1) * 16;
    bf16x8 a, b;
#pragma unroll
    for (int j = 0; j < 8; ++j) {
      a[j] = (__bf16)lv[sh + j][d];
      b[j] = (__bf16)lv[sh + 8 + j][d];
    }
    __bf16* dst = vt + ((size_t)hk * HD + d) * S_LEN + s0 + sh;
    *(bf16x8*)dst = a;
    *(bf16x8*)(dst + 8) = b;
  }
}

// ---------------- flash attention: LDS-staged K/V, KV-group-per-XCD swizzle ----------
__global__ __launch_bounds__(256, 3) void flash_attn(
    const __bf16* __restrict__ q_bf, const __bf16* __restrict__ k_bf,
    const __bf16* __restrict__ vt_bf, __bf16* __restrict__ o_bf) {
  const int t = threadIdx.x;
  const int w = t >> 6, l = t & 63;
  const int b = blockIdx.x;
  const int hk = b & 7;
  const int rem = b >> 3;                 // 0..127
  const int h = hk * 4 + (rem & 3);
  const int qtile = 31 - (rem >> 2);      // big tiles first
  const int q0 = qtile * 64 + w * 16;
  const int lg = l >> 4, li = l & 15;

  __shared__ __attribute__((aligned(16))) __bf16 k_lds[2][32 * 128];
  __shared__ __attribute__((aligned(16))) __bf16 v_lds[2][128 * 32];
  __shared__ __attribute__((aligned(16))) __bf16 p_lds[4][16][40];

  bf16x8 bq[4];
  {
    const __bf16* qp = q_bf + ((size_t)(q0 + li) * NH + h) * HD + lg * 8;
#pragma unroll
    for (int c = 0; c < 4; ++c) bq[c] = *(const bf16x8*)(qp + c * 32);
  }

  float m_r = -1e30f, l_r = 0.f;
  f32x4 o_acc[8];
#pragma unroll
  for (int fd = 0; fd < 8; ++fd) o_acc[fd] = (f32x4){0.f, 0.f, 0.f, 0.f};

  const int nkt = 2 * qtile + 2;

  auto STAGE = [&](int buf, int kb) {
#pragma unroll
    for (int j = 0; j < 2; ++j) {
      const int key = (t >> 4) + j * 16;
      const int csrc = (t & 15) ^ (key & 7);
      gload16(k_bf + (size_t)(kb * 32 + key) * KVSZ + hk * HD + csrc * 8,
              &k_lds[buf][j * 2048 + w * 512]);
    }
#pragma unroll
    for (int j = 0; j < 2; ++j) {
      const int d = (t >> 2) + j * 64;
      const int csrc = (t & 3) ^ (d & 3);
      gload16(vt_bf + ((size_t)hk * HD + d) * S_LEN + kb * 32 + csrc * 8,
              &v_lds[buf][j * 2048 + w * 512]);
    }
  };

  STAGE(0, 0);
  for (int kb = 0; kb < nkt; ++kb) {
    __syncthreads();
    if (kb + 1 < nkt) STAGE((kb + 1) & 1, kb + 1);
    const int cur = kb & 1;

    bf16x8 kr[8];
#pragma unroll
    for (int c = 0; c < 4; ++c) {
      const int ch = ((c * 4 + lg) ^ (li & 7)) * 8;
      kr[c]     = *(const bf16x8*)&k_lds[cur][li * 128 + ch];
      kr[c + 4] = *(const bf16x8*)&k_lds[cur][(li + 16) * 128 + ch];
    }
    f32x4 s0 = {0.f, 0.f, 0.f, 0.f}, s1 = {0.f, 0.f, 0.f, 0.f};
#pragma unroll
    for (int c = 0; c < 4; ++c) {
      s0 = __builtin_amdgcn_mfma_f32_16x16x32_bf16(kr[c],     bq[c], s0, 0, 0, 0);
      s1 = __builtin_amdgcn_mfma_f32_16x16x32_bf16(kr[c + 4], bq[c], s1, 0, 0, 0);
    }
    const int q = q0 + li;
    const int key0 = kb * 32 + lg * 4;
    float v0[4], v1[4];
#pragma unroll
    for (int r = 0; r < 4; ++r) {
      v0[r] = (key0 + r      <= q) ? s0[r] : -1e30f;
      v1[r] = (key0 + r + 16 <= q) ? s1[r] : -1e30f;
    }
    float tm = fmaxf(fmaxf(fmaxf(v0[0], v0[1]), fmaxf(v0[2], v0[3])),
                     fmaxf(fmaxf(v1[0], v1[1]), fmaxf(v1[2], v1[3])));
    tm = fmaxf(tm, __shfl_xor(tm, 16));
    tm = fmaxf(tm, __shfl_xor(tm, 32));
    float mn = fmaxf(m_r, tm);
    float sc = __expf(m_r - mn);
    float e0[4], e1[4], ps = 0.f;
#pragma unroll
    for (int r = 0; r < 4; ++r) {
      e0[r] = __expf(v0[r] - mn);
      e1[r] = __expf(v1[r] - mn);
      ps += e0[r] + e1[r];
    }
    ps += __shfl_xor(ps, 16);
    ps += __shfl_xor(ps, 32);
    l_r = l_r * sc + ps;
    m_r = mn;
#pragma unroll
    for (int r = 0; r < 4; ++r) {
      float scq = __shfl(sc, lg * 4 + r, 16);
#pragma unroll
      for (int fd = 0; fd < 8; ++fd) o_acc[fd][r] *= scq;
    }
    bf16x4 pw0, pw1;
#pragma unroll
    for (int r = 0; r < 4; ++r) { pw0[r] = (__bf16)e0[r]; pw1[r] = (__bf16)e1[r]; }
    *(bf16x4*)&p_lds[w][li][lg * 4]      = pw0;
    *(bf16x4*)&p_lds[w][li][lg * 4 + 16] = pw1;
    bf16x8 pa = *(const bf16x8*)&p_lds[w][li][lg * 8];
#pragma unroll
    for (int fd = 0; fd < 8; ++fd) {
      bf16x8 bv = *(const bf16x8*)&v_lds[cur][(fd * 16 + li) * 32 + ((lg ^ (li & 3)) * 8)];
      o_acc[fd] = __builtin_amdgcn_mfma_f32_16x16x32_bf16(pa, bv, o_acc[fd], 0, 0, 0);
    }
  }

  const size_t obase = (size_t)(q0 + lg * 4) * QSZ + (size_t)h * HD + li;
#pragma unroll
  for (int r = 0; r < 4; ++r) {
    float inv = 1.0f / __shfl(l_r, lg * 4 + r, 16);
#pragma unroll
    for (int fd = 0; fd < 8; ++fd)
      o_bf[obase + (size_t)r * QSZ + fd * 16] = (__bf16)(o_acc[fd][r] * inv);
  }
}

// ---------------- launch ----------------
extern "C" void kernel_launch(void* const* d_in, const int* in_sizes, int n_in,
                              void* d_out, int out_size, void* d_ws, size_t ws_size,
                              hipStream_t stream) {
  const int*   positions = (const int*)d_in[0];
  const float* hidden    = (const float*)d_in[1];
  const float* w_qkv     = (const float*)d_in[2];
  const float* w_o       = (const float*)d_in[3];
  const float* q_norm_w  = (const float*)d_in[4];
  const float* k_norm_w  = (const float*)d_in[5];
  float* out = (float*)d_out;

  char* p = (char*)d_ws;
  float*  qkv = (float*)p;   p += (size_t)S_LEN * QKV_N * 4;   // 50.3 MB
  __bf16* hs  = (__bf16*)p;  p += (size_t)S_LEN * HID * 2;     // 10.5 MB
  __bf16* wq  = (__bf16*)p;  p += (size_t)QKV_N * HID * 2;     // 31.5 MB
  __bf16* wo  = (__bf16*)p;  p += (size_t)HID * QSZ * 2;       // 21.0 MB
  __bf16* qb  = (__bf16*)p;  p += (size_t)S_LEN * QSZ * 2;     // 16.8 MB
  __bf16* kb  = (__bf16*)p;  p += (size_t)S_LEN * KVSZ * 2;    //  4.2 MB
  __bf16* vt  = (__bf16*)p;  p += (size_t)NKV * HD * S_LEN * 2;//  4.2 MB
  __bf16* ob  = (__bf16*)p;  p += (size_t)S_LEN * QSZ * 2;     // 16.8 MB

  castk<<<2048, 256, 0, stream>>>(hidden, hs, S_LEN * HID / 4);
  castk<<<2048, 256, 0, stream>>>(w_qkv, wq, QKV_N * HID / 4);
  castk<<<2048, 256, 0, stream>>>(w_o, wo, HID * QSZ / 4);

  // QKV projection: 8-phase 256^2 template, 128 KiB dynamic LDS
  hipFuncSetAttribute((const void*)gemm256,
                      hipFuncAttributeMaxDynamicSharedMemorySize, 131072);
  gemm256<<<dim3(QKV_N / 256, S_LEN / 256), 512, 131072, stream>>>(
      hs, wq, qkv, S_LEN, QKV_N, HID);

  norm_rope<<<dim3(S_LEN, NH + NKV), 64, 0, stream>>>(qkv, positions, q_norm_w, k_norm_w, qb, kb);
  v_prep<<<dim3(S_LEN / 32, NKV), 256, 0, stream>>>(qkv, vt);

  flash_attn<<<1024, 256, 0, stream>>>(qb, kb, vt, ob);

  gemm_bt<<<dim3(HID / 128, S_LEN / 128), 256, 0, stream>>>(ob, wo, out, S_LEN, HID, QSZ);
}

// Round 9
// 429.153 us; speedup vs baseline: 1.0457x; 1.0457x over previous
//
#include <hip/hip_runtime.h>
#include <hip/hip_bf16.h>

typedef __bf16 bf16x8 __attribute__((ext_vector_type(8)));
typedef __bf16 bf16x4 __attribute__((ext_vector_type(4)));
typedef float f32x4 __attribute__((ext_vector_type(4)));

#define S_LEN 2048
#define HID 2560
#define NH 32
#define NKV 8
#define HD 128
#define QSZ 4096      // NH*HD
#define KVSZ 1024     // NKV*HD
#define QKV_N 6144    // QSZ + 2*KVSZ
#define SCALE_Q 0.08838834764831845f  // 128^-0.5
#define LOG2_THETA 13.287712379549449f // log2(10000)

#define ASM_VMCNT(n) asm volatile("s_waitcnt vmcnt(" #n ")" ::: "memory")
#define ASM_BAR()    asm volatile("s_barrier" ::: "memory")

// ---------------- f32 -> bf16 cast ----------------
__global__ void castk(const float* __restrict__ in, __bf16* __restrict__ out, int n4) {
  int i = blockIdx.x * blockDim.x + threadIdx.x;
  int stride = gridDim.x * blockDim.x;
  for (; i < n4; i += stride) {
    float4 v = ((const float4*)in)[i];
    bf16x4 o;
    o[0] = (__bf16)v.x; o[1] = (__bf16)v.y; o[2] = (__bf16)v.z; o[3] = (__bf16)v.w;
    ((bf16x4*)out)[i] = o;
  }
}

// ---------------- async global->LDS helper ----------------
__device__ __forceinline__ void gload16(const void* g, void* l) {
  __builtin_amdgcn_global_load_lds((const __attribute__((address_space(1))) void*)g,
                                   (__attribute__((address_space(3))) void*)l, 16, 0, 0);
}

// ---------------- 8-phase 256x256 bf16 GEMM: C = A[M][K] * B[N][K]^T ----------------
// 512 threads = 8 waves (2M x 4N), BK=64, 128KiB dynamic LDS = 2 dbuf x 4 half-slots.
// Swizzle f(row) = (row>>1)&3 (NOT row&3: rows 4 apart are 256B = 2 bank-cycles apart,
// so row&3 left li=0,4,8,12 on the same 16B slot -> 4-way conflict, 7.9M counts in r8).
// With (row>>1)&3 a quarter-wave (fixed lg, 16 rows) covers 8 slots x 2 lanes = free.
__global__ __launch_bounds__(512, 2) void gemm256(
    const __bf16* __restrict__ A, const __bf16* __restrict__ B, float* __restrict__ C,
    int M, int N, int K) {
  extern __shared__ __bf16 lds[];   // 65536 elems = 128 KiB
  const int t = threadIdx.x, w = t >> 6, l = t & 63;
  const int wr = w >> 2, wc = w & 3;
  const int lg = l >> 4, li = l & 15;
  const int bn = blockIdx.x, bm = blockIdx.y;
  const int NKT = K >> 6;

  f32x4 acc[8][4];
#pragma unroll
  for (int i = 0; i < 8; ++i)
#pragma unroll
    for (int j = 0; j < 4; ++j) acc[i][j] = (f32x4){0.f, 0.f, 0.f, 0.f};

  // stage half-tile n: slot (n&7), 1024 x 16B, 2 gloads/thread
  auto STG = [&](int n) {
    const int kt = n >> 2, h = n & 3;
    const int kcol = kt * 64 + (h >> 1) * 32;
    __bf16* dst = &lds[(size_t)(((kt & 1) << 2) + h) << 13];
    const __bf16* srcb = (h & 1) ? (B + (size_t)(bn * 256) * K)
                                 : (A + (size_t)(bm * 256) * K);
#pragma unroll
    for (int j = 0; j < 2; ++j) {
      const int idx = j * 512 + t;                      // 0..1023
      const int row = idx >> 2;                         // 0..255
      const int col = (((idx & 3) ^ ((idx >> 3) & 3)) << 3); // chunk ^ (row>>1)&3
      gload16(srcb + (size_t)row * K + kcol + col,
              dst + j * 4096 + w * 512);                // wave-uniform LDS base
    }
  };
  // fragment read from half (buf, h): row lrow, k-chunk lg, swizzled
  auto RD = [&](int buf, int h, int lrow) -> bf16x8 {
    const int off = (lrow << 5) + ((lg ^ ((lrow >> 1) & 3)) << 3);
    return *(const bf16x8*)&lds[((size_t)(((buf << 2) + h)) << 13) + off];
  };

  for (int n = 0; n < 6; ++n) STG(n);
  ASM_VMCNT(8);              // halves 0,1 landed (12 issued - 8)
  ASM_BAR();

  for (int kt = 0; kt < NKT; ++kt) {
    const int buf = kt & 1;
#pragma unroll
    for (int q = 0; q < 4; ++q) {
      const int ks = q >> 1, mh = q & 1;
      bf16x8 a[4], b[4];
#pragma unroll
      for (int i = 0; i < 4; ++i)
        a[i] = RD(buf, ks * 2,     wr * 128 + mh * 64 + i * 16 + li);
#pragma unroll
      for (int j = 0; j < 4; ++j)
        b[j] = RD(buf, ks * 2 + 1, wc * 64 + j * 16 + li);
      const int s = kt * 4 + q;
      if (s + 6 < NKT * 4) STG(s + 6);
      ASM_BAR();
      __builtin_amdgcn_s_setprio(1);
#pragma unroll
      for (int i = 0; i < 4; ++i)
#pragma unroll
        for (int j = 0; j < 4; ++j)
          acc[mh * 4 + i][j] = __builtin_amdgcn_mfma_f32_16x16x32_bf16(
              a[i], b[j], acc[mh * 4 + i][j], 0, 0, 0);
      __builtin_amdgcn_s_setprio(0);
      if (q & 1) {           // K-half boundary: counted wait, drain 8->4->0
        if (s < 4 * NKT - 5)       ASM_VMCNT(8);
        else if (s == 4 * NKT - 5) ASM_VMCNT(4);
        else if (s == 4 * NKT - 3) ASM_VMCNT(0);
      }
      ASM_BAR();
    }
  }

  float* cp = C + (size_t)(bm * 256 + wr * 128 + lg * 4) * N + bn * 256 + wc * 64 + li;
#pragma unroll
  for (int fm = 0; fm < 8; ++fm)
#pragma unroll
    for (int fn = 0; fn < 4; ++fn)
#pragma unroll
      for (int r = 0; r < 4; ++r)
        cp[(size_t)(fm * 16 + r) * N + fn * 16] = acc[fm][fn][r];
}

// ---------------- bf16 GEMM (m97 128^2): C[M][N] = A[M][K] * B[N][K]^T ----------------
__global__ __launch_bounds__(256, 2) void gemm_bt(
    const __bf16* __restrict__ A, const __bf16* __restrict__ B, float* __restrict__ C,
    int M, int N, int K) {
  __shared__ __attribute__((aligned(16))) __bf16 lta[128 * 32];
  __shared__ __attribute__((aligned(16))) __bf16 ltb[128 * 32];
  const int t = threadIdx.x, w = t >> 6, l = t & 63;
  const int bn = blockIdx.x, bm = blockIdx.y;
  const int wr = w >> 1, wc = w & 1;
  const int lg = l >> 4, li = l & 15;

  f32x4 acc[4][4];
#pragma unroll
  for (int i = 0; i < 4; ++i)
#pragma unroll
    for (int j = 0; j < 4; ++j) acc[i][j] = (f32x4){0.f, 0.f, 0.f, 0.f};

  const int nkt = K >> 5;
  const int c0 = w * 2, c1 = w * 2 + 1;
  const int row0 = c0 * 16 + (l >> 2), row1 = c1 * 16 + (l >> 2);
  const int cole = (l & 3) * 8;
  const __bf16* ga = A + (size_t)(bm * 128) * K + cole;
  const __bf16* gb = B + (size_t)(bn * 128) * K + cole;

  for (int kt = 0; kt < nkt; ++kt) {
    const size_t ko = (size_t)kt * 32;
    gload16(ga + (size_t)row0 * K + ko, &lta[c0 * 512]);
    gload16(gb + (size_t)row0 * K + ko, &ltb[c0 * 512]);
    gload16(ga + (size_t)row1 * K + ko, &lta[c1 * 512]);
    gload16(gb + (size_t)row1 * K + ko, &ltb[c1 * 512]);
    __syncthreads();
    bf16x8 af[4], bfr[4];
#pragma unroll
    for (int f = 0; f < 4; ++f) {
      af[f]  = *(const bf16x8*)&lta[(wr * 64 + f * 16 + li) * 32 + lg * 8];
      bfr[f] = *(const bf16x8*)&ltb[(wc * 64 + f * 16 + li) * 32 + lg * 8];
    }
#pragma unroll
    for (int fm = 0; fm < 4; ++fm)
#pragma unroll
      for (int fn = 0; fn < 4; ++fn)
        acc[fm][fn] = __builtin_amdgcn_mfma_f32_16x16x32_bf16(af[fm], bfr[fn], acc[fm][fn], 0, 0, 0);
    __syncthreads();
  }

  float* cp = C + (size_t)(bm * 128 + wr * 64 + lg * 4) * N + bn * 128 + wc * 64 + li;
#pragma unroll
  for (int fm = 0; fm < 4; ++fm)
#pragma unroll
    for (int fn = 0; fn < 4; ++fn)
#pragma unroll
      for (int r = 0; r < 4; ++r)
        cp[(size_t)(fm * 16 + r) * N + fn * 16] = acc[fm][fn][r];
}

// ---------------- fused RMSNorm + RoPE, write bf16 q/k ----------------
__global__ __launch_bounds__(64) void norm_rope(
    const float* __restrict__ qkv, const int* __restrict__ positions,
    const float* __restrict__ qw, const float* __restrict__ kw,
    __bf16* __restrict__ q_bf, __bf16* __restrict__ k_bf) {
  const int s = blockIdx.x, hh = blockIdx.y, l = threadIdx.x;
  const float* row;
  const float* wgt;
  __bf16* outp;
  float scale;
  if (hh < NH) {
    row = qkv + (size_t)s * QKV_N + hh * HD;
    wgt = qw;
    outp = q_bf + ((size_t)s * NH + hh) * HD;
    scale = SCALE_Q;
  } else {
    row = qkv + (size_t)s * QKV_N + QSZ + (hh - NH) * HD;
    wgt = kw;
    outp = k_bf + ((size_t)s * NKV + (hh - NH)) * HD;
    scale = 1.0f;
  }
  float x1 = row[l], x2 = row[l + 64];
  float ss = x1 * x1 + x2 * x2;
#pragma unroll
  for (int off = 32; off; off >>= 1) ss += __shfl_xor(ss, off, 64);
  float rs = rsqrtf(ss * (1.0f / 128.0f) + 1e-6f);
  float n1 = x1 * rs * wgt[l], n2 = x2 * rs * wgt[l + 64];
  float ang = (float)positions[s] * exp2f((float)l * (-LOG2_THETA / 64.0f));
  float sn, cs;
  sincosf(ang, &sn, &cs);
  outp[l]      = (__bf16)((n1 * cs - n2 * sn) * scale);
  outp[l + 64] = (__bf16)((n2 * cs + n1 * sn) * scale);
}

// ---------------- V transpose: qkv f32 -> vt_bf[hk][d][s] ----------------
__global__ __launch_bounds__(256) void v_prep(const float* __restrict__ qkv, __bf16* __restrict__ vt) {
  const int s0 = blockIdx.x * 32, hk = blockIdx.y;
  __shared__ float lv[32][129];
  const int t = threadIdx.x;
  {
    const int s = t >> 3, dseg = (t & 7) * 16;
    const float* src = qkv + (size_t)(s0 + s) * QKV_N + (QSZ + KVSZ) + hk * HD + dseg;
#pragma unroll
    for (int j = 0; j < 4; ++j) {
      float4 v = *(const float4*)(src + j * 4);
      lv[s][dseg + j * 4 + 0] = v.x;
      lv[s][dseg + j * 4 + 1] = v.y;
      lv[s][dseg + j * 4 + 2] = v.z;
      lv[s][dseg + j * 4 + 3] = v.w;
    }
  }
  __syncthreads();
  {
    const int d = t >> 1, sh = (t & 1) * 16;
    bf16x8 a, b;
#pragma unroll
    for (int j = 0; j < 8; ++j) {
      a[j] = (__bf16)lv[sh + j][d];
      b[j] = (__bf16)lv[sh + 8 + j][d];
    }
    __bf16* dst = vt + ((size_t)hk * HD + d) * S_LEN + s0 + sh;
    *(bf16x8*)dst = a;
    *(bf16x8*)(dst + 8) = b;
  }
}

// ---------------- flash attention: LDS-staged K/V, KV-group-per-XCD swizzle ----------
// V swizzle fixed to f(d) = (d>>1)&3 (d&3 had the same 4-way defect as gemm256's r8).
__global__ __launch_bounds__(256, 3) void flash_attn(
    const __bf16* __restrict__ q_bf, const __bf16* __restrict__ k_bf,
    const __bf16* __restrict__ vt_bf, __bf16* __restrict__ o_bf) {
  const int t = threadIdx.x;
  const int w = t >> 6, l = t & 63;
  const int b = blockIdx.x;
  const int hk = b & 7;
  const int rem = b >> 3;                 // 0..127
  const int h = hk * 4 + (rem & 3);
  const int qtile = 31 - (rem >> 2);      // big tiles first
  const int q0 = qtile * 64 + w * 16;
  const int lg = l >> 4, li = l & 15;

  __shared__ __attribute__((aligned(16))) __bf16 k_lds[2][32 * 128];
  __shared__ __attribute__((aligned(16))) __bf16 v_lds[2][128 * 32];
  __shared__ __attribute__((aligned(16))) __bf16 p_lds[4][16][40];

  bf16x8 bq[4];
  {
    const __bf16* qp = q_bf + ((size_t)(q0 + li) * NH + h) * HD + lg * 8;
#pragma unroll
    for (int c = 0; c < 4; ++c) bq[c] = *(const bf16x8*)(qp + c * 32);
  }

  float m_r = -1e30f, l_r = 0.f;
  f32x4 o_acc[8];
#pragma unroll
  for (int fd = 0; fd < 8; ++fd) o_acc[fd] = (f32x4){0.f, 0.f, 0.f, 0.f};

  const int nkt = 2 * qtile + 2;

  auto STAGE = [&](int buf, int kb) {
#pragma unroll
    for (int j = 0; j < 2; ++j) {
      const int key = (t >> 4) + j * 16;
      const int csrc = (t & 15) ^ (key & 7);
      gload16(k_bf + (size_t)(kb * 32 + key) * KVSZ + hk * HD + csrc * 8,
              &k_lds[buf][j * 2048 + w * 512]);
    }
#pragma unroll
    for (int j = 0; j < 2; ++j) {
      const int d = (t >> 2) + j * 64;
      const int csrc = (t & 3) ^ ((d >> 1) & 3);
      gload16(vt_bf + ((size_t)hk * HD + d) * S_LEN + kb * 32 + csrc * 8,
              &v_lds[buf][j * 2048 + w * 512]);
    }
  };

  STAGE(0, 0);
  for (int kb = 0; kb < nkt; ++kb) {
    __syncthreads();
    if (kb + 1 < nkt) STAGE((kb + 1) & 1, kb + 1);
    const int cur = kb & 1;

    bf16x8 kr[8];
#pragma unroll
    for (int c = 0; c < 4; ++c) {
      const int ch = ((c * 4 + lg) ^ (li & 7)) * 8;
      kr[c]     = *(const bf16x8*)&k_lds[cur][li * 128 + ch];
      kr[c + 4] = *(const bf16x8*)&k_lds[cur][(li + 16) * 128 + ch];
    }
    f32x4 s0 = {0.f, 0.f, 0.f, 0.f}, s1 = {0.f, 0.f, 0.f, 0.f};
#pragma unroll
    for (int c = 0; c < 4; ++c) {
      s0 = __builtin_amdgcn_mfma_f32_16x16x32_bf16(kr[c],     bq[c], s0, 0, 0, 0);
      s1 = __builtin_amdgcn_mfma_f32_16x16x32_bf16(kr[c + 4], bq[c], s1, 0, 0, 0);
    }
    const int q = q0 + li;
    const int key0 = kb * 32 + lg * 4;
    float v0[4], v1[4];
#pragma unroll
    for (int r = 0; r < 4; ++r) {
      v0[r] = (key0 + r      <= q) ? s0[r] : -1e30f;
      v1[r] = (key0 + r + 16 <= q) ? s1[r] : -1e30f;
    }
    float tm = fmaxf(fmaxf(fmaxf(v0[0], v0[1]), fmaxf(v0[2], v0[3])),
                     fmaxf(fmaxf(v1[0], v1[1]), fmaxf(v1[2], v1[3])));
    tm = fmaxf(tm, __shfl_xor(tm, 16));
    tm = fmaxf(tm, __shfl_xor(tm, 32));
    float mn = fmaxf(m_r, tm);
    float sc = __expf(m_r - mn);
    float e0[4], e1[4], ps = 0.f;
#pragma unroll
    for (int r = 0; r < 4; ++r) {
      e0[r] = __expf(v0[r] - mn);
      e1[r] = __expf(v1[r] - mn);
      ps += e0[r] + e1[r];
    }
    ps += __shfl_xor(ps, 16);
    ps += __shfl_xor(ps, 32);
    l_r = l_r * sc + ps;
    m_r = mn;
#pragma unroll
    for (int r = 0; r < 4; ++r) {
      float scq = __shfl(sc, lg * 4 + r, 16);
#pragma unroll
      for (int fd = 0; fd < 8; ++fd) o_acc[fd][r] *= scq;
    }
    bf16x4 pw0, pw1;
#pragma unroll
    for (int r = 0; r < 4; ++r) { pw0[r] = (__bf16)e0[r]; pw1[r] = (__bf16)e1[r]; }
    *(bf16x4*)&p_lds[w][li][lg * 4]      = pw0;
    *(bf16x4*)&p_lds[w][li][lg * 4 + 16] = pw1;
    bf16x8 pa = *(const bf16x8*)&p_lds[w][li][lg * 8];
#pragma unroll
    for (int fd = 0; fd < 8; ++fd) {
      // row = fd*16+li -> f(row) = ((row>>1)&3) = ((li>>1)&3)
      bf16x8 bv = *(const bf16x8*)&v_lds[cur][(fd * 16 + li) * 32 + ((lg ^ ((li >> 1) & 3)) * 8)];
      o_acc[fd] = __builtin_amdgcn_mfma_f32_16x16x32_bf16(pa, bv, o_acc[fd], 0, 0, 0);
    }
  }

  const size_t obase = (size_t)(q0 + lg * 4) * QSZ + (size_t)h * HD + li;
#pragma unroll
  for (int r = 0; r < 4; ++r) {
    float inv = 1.0f / __shfl(l_r, lg * 4 + r, 16);
#pragma unroll
    for (int fd = 0; fd < 8; ++fd)
      o_bf[obase + (size_t)r * QSZ + fd * 16] = (__bf16)(o_acc[fd][r] * inv);
  }
}

// ---------------- launch ----------------
extern "C" void kernel_launch(void* const* d_in, const int* in_sizes, int n_in,
                              void* d_out, int out_size, void* d_ws, size_t ws_size,
                              hipStream_t stream) {
  const int*   positions = (const int*)d_in[0];
  const float* hidden    = (const float*)d_in[1];
  const float* w_qkv     = (const float*)d_in[2];
  const float* w_o       = (const float*)d_in[3];
  const float* q_norm_w  = (const float*)d_in[4];
  const float* k_norm_w  = (const float*)d_in[5];
  float* out = (float*)d_out;

  char* p = (char*)d_ws;
  float*  qkv = (float*)p;   p += (size_t)S_LEN * QKV_N * 4;   // 50.3 MB
  __bf16* hs  = (__bf16*)p;  p += (size_t)S_LEN * HID * 2;     // 10.5 MB
  __bf16* wq  = (__bf16*)p;  p += (size_t)QKV_N * HID * 2;     // 31.5 MB
  __bf16* wo  = (__bf16*)p;  p += (size_t)HID * QSZ * 2;       // 21.0 MB
  __bf16* qb  = (__bf16*)p;  p += (size_t)S_LEN * QSZ * 2;     // 16.8 MB
  __bf16* kb  = (__bf16*)p;  p += (size_t)S_LEN * KVSZ * 2;    //  4.2 MB
  __bf16* vt  = (__bf16*)p;  p += (size_t)NKV * HD * S_LEN * 2;//  4.2 MB
  __bf16* ob  = (__bf16*)p;  p += (size_t)S_LEN * QSZ * 2;     // 16.8 MB

  castk<<<2048, 256, 0, stream>>>(hidden, hs, S_LEN * HID / 4);
  castk<<<2048, 256, 0, stream>>>(w_qkv, wq, QKV_N * HID / 4);
  castk<<<2048, 256, 0, stream>>>(w_o, wo, HID * QSZ / 4);

  // QKV projection: 8-phase 256^2 template, 128 KiB dynamic LDS
  hipFuncSetAttribute((const void*)gemm256,
                      hipFuncAttributeMaxDynamicSharedMemorySize, 131072);
  gemm256<<<dim3(QKV_N / 256, S_LEN / 256), 512, 131072, stream>>>(
      hs, wq, qkv, S_LEN, QKV_N, HID);

  norm_rope<<<dim3(S_LEN, NH + NKV), 64, 0, stream>>>(qkv, positions, q_norm_w, k_norm_w, qb, kb);
  v_prep<<<dim3(S_LEN / 32, NKV), 256, 0, stream>>>(qkv, vt);

  flash_attn<<<1024, 256, 0, stream>>>(qb, kb, vt, ob);

  gemm_bt<<<dim3(HID / 128, S_LEN / 128), 256, 0, stream>>>(ob, wo, out, S_LEN, HID, QSZ);
}